// Round 6
// baseline (338.773 us; speedup 1.0000x reference)
//
#include <hip/hip_runtime.h>
#include <stdint.h>

#define HDIM 64
#define TDIM 512
#define GB   16   // batches per wave (one MFMA N-tile)

// ---- Fully register-resident transposed-MFMA RNN ----
// Round-5 lesson: per-step cost was the fixed LDS round-trip + 2 barriers
// (C-layout -> A-layout relayout of h across waves), not math. Fix: compute
// the TRANSPOSED update  S_new[64h x 16b] = tanh(xw + W_hh * S)  so the
// state is the MFMA *B-operand* (N = batch = 16 = one tile, M = h-dim = 4
// tiles). D's col index (lane&15) == B's col index (lane&15); the row/k
// mismatch (D row 4g+r of tile m  vs  B k = 32c+8g+e) is absorbed by a
// STATIC row-permutation of W_hh:
//     phi(16m+4g+r) = 32*(m&1) + 8*g + 4*(m>>1) + r
// applied to W_hh rows, W_ih, biases, fc_w at load time (free). Then the
// tanh'd, f16-hi/lo-packed D registers ARE the next step's B-frags: zero
// LDS for h, zero barriers, one wave per 16 batches, everything register-
// resident. tanh arg pre-scaled by K=2*log2(e) (folded into W and bias) so
// exp2 needs no multiply.
// waves_per_eu(1,1): 256 waves total (1/CU) by construction; give the
// allocator the full 512-VGPR budget so W (64 regs) + consts (32) + state
// (32) never spill (rounds 0-3 showed the default 8-wave occupancy target
// silently spills to AGPR/scratch).
//
// Layouts (16x16x32 f16, verified numerically in rounds 4-5):
//   A: row = lane&15, k = 8*(lane>>4)+e   (per 32-wide chunk)
//   B: col = lane&15, k = 8*(lane>>4)+e
//   C/D: col = lane&15, row = 4*(lane>>4)+reg

typedef float    f32x4 __attribute__((ext_vector_type(4)));
typedef _Float16 f16x8 __attribute__((ext_vector_type(8)));

__global__ __launch_bounds__(64)
__attribute__((amdgpu_waves_per_eu(1, 1)))
void rnn_reg_resident(const float* __restrict__ x,
                      const float* __restrict__ W_ih,
                      const float* __restrict__ W_hh,
                      const float* __restrict__ b_ih,
                      const float* __restrict__ b_hh,
                      const float* __restrict__ fc_w,
                      const float* __restrict__ fc_b,
                      float* __restrict__ out,
                      int B)
{
    __shared__ float xs[64][GB];     // x chunk [t_local][b], 4 KB, wave-private

    const int lane = threadIdx.x;    // block = 1 wave
    const int b    = lane & 15;      // batch col (B-operand / D col)
    const int g    = lane >> 4;      // k-group / D row-group
    const int gb0  = blockIdx.x * GB;

    const float K = 2.885390081777927f;   // 2*log2(e), folded into W & bias

    // ---- A-frags: W'[M,k] = K * W_hh[phi(M), k], f16 hi/lo ----
    // A row-in-tile = lane&15 ; global row M = 16m + (lane&15)
    f16x8 Ahi[4][2], Alo[4][2];
    const int m16 = lane & 15;
#pragma unroll
    for (int m = 0; m < 4; ++m) {
        const int wr = 32 * (m & 1) + 8 * (m16 >> 2) + 4 * (m >> 1) + (m16 & 3);
        const float* wrow = W_hh + wr * HDIM;
#pragma unroll
        for (int c = 0; c < 2; ++c) {
            const f32x4 va = *(const f32x4*)(wrow + 32 * c + 8 * g);
            const f32x4 vb = *(const f32x4*)(wrow + 32 * c + 8 * g + 4);
#pragma unroll
            for (int e = 0; e < 4; ++e) {
                const float v0 = K * va[e], v1 = K * vb[e];
                const _Float16 h0 = (_Float16)v0, h1 = (_Float16)v1;
                Ahi[m][c][e]     = h0;  Alo[m][c][e]     = (_Float16)(v0 - (float)h0);
                Ahi[m][c][e + 4] = h1;  Alo[m][c][e + 4] = (_Float16)(v1 - (float)h1);
            }
        }
    }

    // ---- per-lane C-init constants: rows M = 16m+4g+r -> h-index phi(M) ----
    float wihc[4][4], biasc[4][4];
#pragma unroll
    for (int m = 0; m < 4; ++m)
#pragma unroll
        for (int r = 0; r < 4; ++r) {
            const int idx = 32 * (m & 1) + 8 * g + 4 * (m >> 1) + r;
            wihc[m][r]  = K * W_ih[idx];
            biasc[m][r] = K * (b_ih[idx] + b_hh[idx]);
        }

    // ---- state B-frags (chunk 0/1, hi/lo), two sets for ping-pong ----
    f16x8 z8;
#pragma unroll
    for (int e = 0; e < 8; ++e) z8[e] = (_Float16)0.0f;
    f16x8 bh0_1 = z8, bh1_1 = z8, bl0_1 = z8, bl1_1 = z8;   // h(t=0) = 0
    f16x8 bh0_2 = z8, bh1_2 = z8, bl0_2 = z8, bl1_2 = z8;

    // ---- x prefetch: lane stages 16 t's of row sb (coalesced-ish) ----
    const int sb = lane >> 2;        // batch row 0..15
    const int sq = lane & 3;         // 16-t subchunk
    const float* xrow = x + (size_t)(gb0 + sb) * TDIM + sq * 16;
    f32x4 p0 = *(const f32x4*)(xrow + 0);
    f32x4 p1 = *(const f32x4*)(xrow + 4);
    f32x4 p2 = *(const f32x4*)(xrow + 8);
    f32x4 p3 = *(const f32x4*)(xrow + 12);

    // One timestep: read set I*, write set O*. D(tile m, reg r) -> B slot
    // (chunk c = m&1, elem e = 4*(m>>1)+r), SAME lane.
#define STEP(T, IH0, IH1, IL0, IL1, OH0, OH1, OL0, OL1)                       \
    {                                                                         \
        const float xt = xs[(T)][b];                                          \
        float hv[4][4];                                                       \
        _Pragma("unroll")                                                     \
        for (int m = 0; m < 4; ++m) {                                         \
            f32x4 c1, c2;                                                     \
            c1.x = fmaf(xt, wihc[m][0], biasc[m][0]);                         \
            c1.y = fmaf(xt, wihc[m][1], biasc[m][1]);                         \
            c1.z = fmaf(xt, wihc[m][2], biasc[m][2]);                         \
            c1.w = fmaf(xt, wihc[m][3], biasc[m][3]);                         \
            c2 = (f32x4){0.f, 0.f, 0.f, 0.f};                                 \
            c1 = __builtin_amdgcn_mfma_f32_16x16x32_f16(Ahi[m][0], IH0, c1, 0, 0, 0); \
            c2 = __builtin_amdgcn_mfma_f32_16x16x32_f16(Ahi[m][0], IL0, c2, 0, 0, 0); \
            c2 = __builtin_amdgcn_mfma_f32_16x16x32_f16(Alo[m][0], IH0, c2, 0, 0, 0); \
            c1 = __builtin_amdgcn_mfma_f32_16x16x32_f16(Ahi[m][1], IH1, c1, 0, 0, 0); \
            c2 = __builtin_amdgcn_mfma_f32_16x16x32_f16(Ahi[m][1], IL1, c2, 0, 0, 0); \
            c2 = __builtin_amdgcn_mfma_f32_16x16x32_f16(Alo[m][1], IH1, c2, 0, 0, 0); \
            _Pragma("unroll")                                                 \
            for (int r = 0; r < 4; ++r) {                                     \
                const float zz = c1[r] + c2[r];        /* already K-scaled */ \
                const float ee = __builtin_amdgcn_exp2f(zz);                  \
                const float qq = __builtin_amdgcn_rcpf(ee + 1.0f);            \
                hv[m][r] = fmaf(-2.0f, qq, 1.0f);      /* tanh */             \
            }                                                                 \
        }                                                                     \
        _Pragma("unroll")                                                     \
        for (int m = 0; m < 4; ++m)                                           \
            _Pragma("unroll")                                                 \
            for (int r = 0; r < 4; ++r) {                                     \
                const int e = 4 * (m >> 1) + r;                               \
                const float hvf = hv[m][r];                                   \
                const _Float16 hi = (_Float16)hvf;                            \
                const _Float16 lo = (_Float16)(hvf - (float)hi);              \
                if (m & 1) { OH1[e] = hi; OL1[e] = lo; }                      \
                else       { OH0[e] = hi; OL0[e] = lo; }                      \
            }                                                                 \
    }

#pragma unroll 1
    for (int tc = 0; tc < TDIM / 64; ++tc) {
        // stage prefetched chunk into xs[t][b]  (wave-private, in-order DS
        // pipe orders these after the previous chunk's reads -> no barrier)
#pragma unroll
        for (int q = 0; q < 4; ++q) {
            const f32x4 pv = (q == 0) ? p0 : (q == 1) ? p1 : (q == 2) ? p2 : p3;
#pragma unroll
            for (int j = 0; j < 4; ++j)
                xs[sq * 16 + q * 4 + j][sb] = pv[j];
        }
        if (tc + 1 < TDIM / 64) {
            const float* nxt = xrow + (tc + 1) * 64;
            p0 = *(const f32x4*)(nxt + 0);
            p1 = *(const f32x4*)(nxt + 4);
            p2 = *(const f32x4*)(nxt + 8);
            p3 = *(const f32x4*)(nxt + 12);
        }

#pragma unroll 1
        for (int t = 0; t < 64; t += 2) {
            STEP(t,     bh0_1, bh1_1, bl0_1, bl1_1,  bh0_2, bh1_2, bl0_2, bl1_2)
            STEP(t + 1, bh0_2, bh1_2, bl0_2, bl1_2,  bh0_1, bh1_1, bl0_1, bl1_1)
        }
    }
#undef STEP

    // ---- out[b] = sum_k h[k]*fc_w[k] + fc_b ----
    // Final state (512 steps, even) is in set 1. Slot (c,e) holds
    // h[32c + 8g + e] as hi+lo (exact reconstruction).
    float acc = 0.0f;
#pragma unroll
    for (int c = 0; c < 2; ++c)
#pragma unroll
        for (int e = 0; e < 8; ++e) {
            const float hvf = (c == 0)
                ? ((float)bh0_1[e] + (float)bl0_1[e])
                : ((float)bh1_1[e] + (float)bl1_1[e]);
            acc = fmaf(hvf, fc_w[32 * c + 8 * g + e], acc);
        }
    acc += __shfl_xor(acc, 16, 64);   // sum over the 4 g-groups of this col
    acc += __shfl_xor(acc, 32, 64);
    if (lane < 16)
        out[gb0 + lane] = acc + fc_b[0];
}

extern "C" void kernel_launch(void* const* d_in, const int* in_sizes, int n_in,
                              void* d_out, int out_size, void* d_ws, size_t ws_size,
                              hipStream_t stream)
{
    const float* x    = (const float*)d_in[0];
    const float* W_ih = (const float*)d_in[1];
    const float* W_hh = (const float*)d_in[2];
    const float* b_ih = (const float*)d_in[3];
    const float* b_hh = (const float*)d_in[4];
    const float* fc_w = (const float*)d_in[5];
    const float* fc_b = (const float*)d_in[6];
    float* out = (float*)d_out;

    const int B = in_sizes[0] / TDIM;      // x is (B, T, 1)
    const int blocks = B / GB;             // 256 blocks x 1 wave

    rnn_reg_resident<<<blocks, 64, 0, stream>>>(
        x, W_ih, W_hh, b_ih, b_hh, fc_w, fc_b, out, B);
}

// Round 7
// 326.398 us; speedup vs baseline: 1.0379x; 1.0379x over previous
//
#include <hip/hip_runtime.h>
#include <stdint.h>

#define HDIM 64
#define TDIM 512
#define GB   16   // batches per wave (one MFMA N-tile)

// ---- Register-resident transposed-MFMA RNN, slim epilogue ----
// r6 counters: 256 waves (1/CU), active SIMDs ~78% VALU-busy -> ISSUE-bound,
// ~1040 busy-cy/step. Breakdown: tanh core ~96 cy, cinit ~64, pack/split
// ~200-250 cy (cvt/cvt-back/sub/cvt + element inserts), trans 256-512 cy.
// r7 cuts the pack/split:
//   - hi/lo split by BIT-MASK: hi = bitcast(h)&0xFFFFE000 (exactly f16-
//     representable), lo = h - hi  -> 2 VALU/output instead of 4 cvts.
//   - pack via v_cvt_pkrtz_f16_f32 (1 op -> packed dword); state kept as
//     16 u32 dwords bit-cast directly into MFMA B-operands. 8 pkrtz/step
//     replaces ~32 cvt + ~32 insert.
//   - c2 zero-acc hoisted; x_t prefetched one step ahead (LDS latency off
//     the critical path).
// Everything else identical to r6 (verified absmax 9.8e-4): transposed
// update S_new[64h x 16b] = tanh(xw + W_hh*S), state = B-operand, static
// row-permutation phi(16m+4g+r)=32(m&1)+8g+4(m>>1)+r makes D->B identity
// in lane space; K=2*log2(e) folded into W/bias so exp2 needs no multiply.

typedef float    f32x4 __attribute__((ext_vector_type(4)));
typedef _Float16 f16x8 __attribute__((ext_vector_type(8)));
typedef _Float16 f16x2 __attribute__((ext_vector_type(2)));
typedef unsigned int u32;
typedef unsigned int u32x4 __attribute__((ext_vector_type(4)));

__device__ __forceinline__ u32 pk2(float a, float b) {
    return __builtin_bit_cast(u32, __builtin_amdgcn_cvt_pkrtz(a, b));
}
__device__ __forceinline__ f16x8 mk8(u32 a, u32 b, u32 c, u32 d) {
    u32x4 t; t.x = a; t.y = b; t.z = c; t.w = d;
    return __builtin_bit_cast(f16x8, t);
}
__device__ __forceinline__ float hi_mask(float v) {
    return __builtin_bit_cast(float, __builtin_bit_cast(u32, v) & 0xFFFFE000u);
}

__global__ __launch_bounds__(64)
__attribute__((amdgpu_waves_per_eu(1, 1)))
void rnn_reg_slim(const float* __restrict__ x,
                  const float* __restrict__ W_ih,
                  const float* __restrict__ W_hh,
                  const float* __restrict__ b_ih,
                  const float* __restrict__ b_hh,
                  const float* __restrict__ fc_w,
                  const float* __restrict__ fc_b,
                  float* __restrict__ out,
                  int B)
{
    __shared__ float xs[66][GB];     // x chunk [t_local][b] (+2 pad rows for
                                     // harmless over-prefetch at chunk end)

    const int lane = threadIdx.x;    // block = 1 wave
    const int b    = lane & 15;      // batch col (B-operand / D col)
    const int g    = lane >> 4;      // k-group / D row-group
    const int gb0  = blockIdx.x * GB;

    const float K = 2.885390081777927f;   // 2*log2(e), folded into W & bias

    // ---- A-frags: W'[M,k] = K * W_hh[phi(M), k], f16 hi/lo ----
    f16x8 Ahi[4][2], Alo[4][2];
    const int m16 = lane & 15;
#pragma unroll
    for (int m = 0; m < 4; ++m) {
        const int wr = 32 * (m & 1) + 8 * (m16 >> 2) + 4 * (m >> 1) + (m16 & 3);
        const float* wrow = W_hh + wr * HDIM;
#pragma unroll
        for (int c = 0; c < 2; ++c) {
            const f32x4 va = *(const f32x4*)(wrow + 32 * c + 8 * g);
            const f32x4 vb = *(const f32x4*)(wrow + 32 * c + 8 * g + 4);
#pragma unroll
            for (int e = 0; e < 4; ++e) {
                const float v0 = K * va[e], v1 = K * vb[e];
                const _Float16 h0 = (_Float16)v0, h1 = (_Float16)v1;
                Ahi[m][c][e]     = h0;  Alo[m][c][e]     = (_Float16)(v0 - (float)h0);
                Ahi[m][c][e + 4] = h1;  Alo[m][c][e + 4] = (_Float16)(v1 - (float)h1);
            }
        }
    }

    // ---- per-lane C-init constants: rows M = 16m+4g+r -> h-index phi(M) ----
    float wihc[4][4], biasc[4][4];
#pragma unroll
    for (int m = 0; m < 4; ++m)
#pragma unroll
        for (int r = 0; r < 4; ++r) {
            const int idx = 32 * (m & 1) + 8 * g + 4 * (m >> 1) + r;
            wihc[m][r]  = K * W_ih[idx];
            biasc[m][r] = K * (b_ih[idx] + b_hh[idx]);
        }

    // ---- state: 16 u32 dwords per set (chunk0 hi[0..3] lo[4..7],
    //      chunk1 hi[8..11] lo[12..15]); ping-pong sets SA/SB ----
    u32 SA[16], SB[16];
#pragma unroll
    for (int i = 0; i < 16; ++i) { SA[i] = 0u; SB[i] = 0u; }   // h(t=0)=0

    const f32x4 zero4 = {0.f, 0.f, 0.f, 0.f};

    // ---- x prefetch: lane stages 16 t's of row sb ----
    const int sb = lane >> 2;        // batch row 0..15
    const int sq = lane & 3;         // 16-t subchunk
    const float* xrow = x + (size_t)(gb0 + sb) * TDIM + sq * 16;
    f32x4 p0 = *(const f32x4*)(xrow + 0);
    f32x4 p1 = *(const f32x4*)(xrow + 4);
    f32x4 p2 = *(const f32x4*)(xrow + 8);
    f32x4 p3 = *(const f32x4*)(xrow + 12);

    // One timestep: consume XT, prefetch next x into XN (offset NOFF floats),
    // read state IN[], write state OUT[]. D(tile m, reg r) -> state slot
    // (chunk c = m&1, elem e = 4*(m>>1)+r), same lane.
#define STEP(XT, XN, NOFF, IN, OUT)                                           \
    {                                                                         \
        XN = xp[NOFF];                                                        \
        const f16x8 IH0 = mk8(IN[0],  IN[1],  IN[2],  IN[3]);                 \
        const f16x8 IL0 = mk8(IN[4],  IN[5],  IN[6],  IN[7]);                 \
        const f16x8 IH1 = mk8(IN[8],  IN[9],  IN[10], IN[11]);                \
        const f16x8 IL1 = mk8(IN[12], IN[13], IN[14], IN[15]);                \
        _Pragma("unroll")                                                     \
        for (int m = 0; m < 4; ++m) {                                         \
            f32x4 c1;                                                         \
            c1.x = fmaf(XT, wihc[m][0], biasc[m][0]);                         \
            c1.y = fmaf(XT, wihc[m][1], biasc[m][1]);                         \
            c1.z = fmaf(XT, wihc[m][2], biasc[m][2]);                         \
            c1.w = fmaf(XT, wihc[m][3], biasc[m][3]);                         \
            f32x4 c2 = zero4;                                                 \
            c1 = __builtin_amdgcn_mfma_f32_16x16x32_f16(Ahi[m][0], IH0, c1, 0, 0, 0); \
            c2 = __builtin_amdgcn_mfma_f32_16x16x32_f16(Ahi[m][0], IL0, c2, 0, 0, 0); \
            c2 = __builtin_amdgcn_mfma_f32_16x16x32_f16(Alo[m][0], IH0, c2, 0, 0, 0); \
            c1 = __builtin_amdgcn_mfma_f32_16x16x32_f16(Ahi[m][1], IH1, c1, 0, 0, 0); \
            c2 = __builtin_amdgcn_mfma_f32_16x16x32_f16(Ahi[m][1], IL1, c2, 0, 0, 0); \
            c2 = __builtin_amdgcn_mfma_f32_16x16x32_f16(Alo[m][1], IH1, c2, 0, 0, 0); \
            float hv[4];                                                      \
            _Pragma("unroll")                                                 \
            for (int r = 0; r < 4; ++r) {                                     \
                const float zz = c1[r] + c2[r];        /* K-scaled */         \
                const float ee = __builtin_amdgcn_exp2f(zz);                  \
                const float qq = __builtin_amdgcn_rcpf(ee + 1.0f);            \
                hv[r] = fmaf(-2.0f, qq, 1.0f);         /* tanh */             \
            }                                                                 \
            const float h0 = hi_mask(hv[0]), h1 = hi_mask(hv[1]);             \
            const float h2 = hi_mask(hv[2]), h3 = hi_mask(hv[3]);             \
            const int s = (m & 1) * 8 + (m >> 1) * 2;                         \
            OUT[s + 0] = pk2(h0, h1);                                         \
            OUT[s + 1] = pk2(h2, h3);                                         \
            OUT[s + 4] = pk2(hv[0] - h0, hv[1] - h1);                         \
            OUT[s + 5] = pk2(hv[2] - h2, hv[3] - h3);                         \
        }                                                                     \
    }

    const float* const xp0 = &xs[0][b];

#pragma unroll 1
    for (int tc = 0; tc < TDIM / 64; ++tc) {
        // stage prefetched chunk into xs[t][b] (wave-private; compiler
        // orders the subsequent reads after these writes)
#pragma unroll
        for (int q = 0; q < 4; ++q) {
            const f32x4 pv = (q == 0) ? p0 : (q == 1) ? p1 : (q == 2) ? p2 : p3;
#pragma unroll
            for (int j = 0; j < 4; ++j)
                xs[sq * 16 + q * 4 + j][sb] = pv[j];
        }
        if (tc + 1 < TDIM / 64) {
            const float* nxt = xrow + (tc + 1) * 64;
            p0 = *(const f32x4*)(nxt + 0);
            p1 = *(const f32x4*)(nxt + 4);
            p2 = *(const f32x4*)(nxt + 8);
            p3 = *(const f32x4*)(nxt + 12);
        }

        const float* xp = xp0;
        float xt = xp[0], xn;
#pragma unroll 1
        for (int u = 0; u < 32; ++u) {
            STEP(xt, xn, 16, SA, SB)     // step 2u   : SA -> SB, prefetch t+1
            STEP(xn, xt, 32, SB, SA)     // step 2u+1 : SB -> SA, prefetch t+2
            xp += 32;
        }
    }
#undef STEP

    // ---- out[b] = sum_k h[k]*fc_w[k] + fc_b  (final state in SA) ----
    float acc = 0.0f;
#pragma unroll
    for (int c = 0; c < 2; ++c)
#pragma unroll
        for (int d = 0; d < 4; ++d) {
            const f16x2 hh2 = __builtin_bit_cast(f16x2, SA[c * 8 + d]);
            const f16x2 ll2 = __builtin_bit_cast(f16x2, SA[c * 8 + 4 + d]);
            const float v0 = (float)hh2.x + (float)ll2.x;
            const float v1 = (float)hh2.y + (float)ll2.y;
            acc = fmaf(v0, fc_w[32 * c + 8 * g + 2 * d + 0], acc);
            acc = fmaf(v1, fc_w[32 * c + 8 * g + 2 * d + 1], acc);
        }
    acc += __shfl_xor(acc, 16, 64);   // sum the 4 g-groups of this col
    acc += __shfl_xor(acc, 32, 64);
    if (lane < 16)
        out[gb0 + lane] = acc + fc_b[0];
}

extern "C" void kernel_launch(void* const* d_in, const int* in_sizes, int n_in,
                              void* d_out, int out_size, void* d_ws, size_t ws_size,
                              hipStream_t stream)
{
    const float* x    = (const float*)d_in[0];
    const float* W_ih = (const float*)d_in[1];
    const float* W_hh = (const float*)d_in[2];
    const float* b_ih = (const float*)d_in[3];
    const float* b_hh = (const float*)d_in[4];
    const float* fc_w = (const float*)d_in[5];
    const float* fc_b = (const float*)d_in[6];
    float* out = (float*)d_out;

    const int B = in_sizes[0] / TDIM;      // x is (B, T, 1)
    const int blocks = B / GB;             // 256 blocks x 1 wave

    rnn_reg_slim<<<blocks, 64, 0, stream>>>(
        x, W_ih, W_hh, b_ih, b_hh, fc_w, fc_b, out, B);
}

// Round 9
// 259.224 us; speedup vs baseline: 1.3069x; 1.2591x over previous
//
#include <hip/hip_runtime.h>
#include <stdint.h>

#define HDIM 64
#define TDIM 512
#define GB   16   // batches per block (one MFMA N-tile)

// ---- 4-wave, single-slot two-barrier MFMA RNN ----
// Transposed update S_new[64h x 16b] = tanh(xw + W'*S); state = B-operand.
// Wave w owns output tile w (16 rows). Static row-permutation
//   phi(16w+4g+r) = 32*(w>>1) + 8g + 4*(w&1) + r
// (applied to W_hh rows, W_ih, biases, fc_w at load -> free) makes wave w's
// packed D registers exactly dwords [2w, 2w+1] of the next step's
// B-fragments, SAME lane. State exchange: st[q][64 lanes][4 dwords], q =
// {hi-chunk0, hi-chunk1, lo-chunk0, lo-chunk1}; each wave writes one b64
// per q-pair; every wave reads 4 aligned lane-contiguous ds_read_b128 --
// conflict-free (vs r4's swizzled 128B-stride reads, 983K conflicts).
// Protocol (bulletproof, no ping-pong): read h(t) -> compute -> BARRIER
// (everyone done reading) -> write h(t+1) -> BARRIER (visible). r8's
// parity ping-pong (failed, bug unlocated) is fully removed.
// Numerics = r4/r7 verified: f16 hi/lo split on W and state (3-term
// product, f32 acc), K=2*log2(e) folded into W/bias so exp2 is direct,
// bit-mask hi split + cvt_pkrtz pack. Epilogue: 4 outputs/lane.
// 256 blocks x 4 waves = 1024 waves = 1/SIMD, full chip.
//
// Layouts (16x16x32 f16, HW-verified r4-r7):
//   A: row = lane&15, k = 8*(lane>>4)+e     B: col = lane&15, same k-map
//   C/D: col = lane&15, row = 4*(lane>>4)+reg

typedef float    f32x4 __attribute__((ext_vector_type(4)));
typedef _Float16 f16x8 __attribute__((ext_vector_type(8)));
typedef _Float16 f16x2 __attribute__((ext_vector_type(2)));
typedef unsigned int u32;
typedef unsigned int u32x2 __attribute__((ext_vector_type(2)));
typedef unsigned int u32x4 __attribute__((ext_vector_type(4)));

__device__ __forceinline__ u32 pk2(float a, float b) {
    return __builtin_bit_cast(u32, __builtin_amdgcn_cvt_pkrtz(a, b));
}
__device__ __forceinline__ float hi_mask(float v) {
    // top-13-mantissa-bit truncation: exactly representable in f16 for |v|<=1
    return __builtin_bit_cast(float, __builtin_bit_cast(u32, v) & 0xFFFFE000u);
}

__global__ __launch_bounds__(256, 1)
__attribute__((amdgpu_waves_per_eu(1)))   // budget 512 VGPR; live set ~80
void rnn_quadwave(const float* __restrict__ x,
                  const float* __restrict__ W_ih,
                  const float* __restrict__ W_hh,
                  const float* __restrict__ b_ih,
                  const float* __restrict__ b_hh,
                  const float* __restrict__ fc_w,
                  const float* __restrict__ fc_b,
                  float* __restrict__ out,
                  int B)
{
    __shared__ __align__(16) u32 st[4][64][4];  // 4 KB state exchange
    __shared__ float xs[64][GB];                // 4 KB x chunk [t][batch]
    __shared__ float red[4][GB];                // final reduction

    const int tid  = threadIdx.x;               // block = 4 waves
    const int lane = tid & 63;
    const int w    = tid >> 6;                  // wave id = output tile
    const int b    = lane & 15;                 // batch col (B/D col)
    const int g    = lane >> 4;                 // k-group / D row-group
    const int m16  = lane & 15;
    const int gb0  = blockIdx.x * GB;
    const int wc   = w >> 1;                    // chunk this wave feeds
    const int wh   = w & 1;                     // dword-pair within chunk

    const float K = 2.885390081777927f;         // 2*log2(e), folded into W & bias

    // ---- A-frags (tile w): rows phi(16w + m16), f16 hi/lo, K-scaled ----
    f16x8 Ahi0, Ahi1, Alo0, Alo1;               // chunk 0 / chunk 1
    {
        const int wr = 32*wc + 8*(m16 >> 2) + 4*wh + (m16 & 3);
        const float* wrow = W_hh + wr * HDIM;
        const f32x4 va0 = *(const f32x4*)(wrow + 8*g);
        const f32x4 vb0 = *(const f32x4*)(wrow + 8*g + 4);
        const f32x4 va1 = *(const f32x4*)(wrow + 32 + 8*g);
        const f32x4 vb1 = *(const f32x4*)(wrow + 32 + 8*g + 4);
#pragma unroll
        for (int e = 0; e < 4; ++e) {
            float v; _Float16 h;
            v = K*va0[e]; h = (_Float16)v; Ahi0[e]   = h; Alo0[e]   = (_Float16)(v - (float)h);
            v = K*vb0[e]; h = (_Float16)v; Ahi0[e+4] = h; Alo0[e+4] = (_Float16)(v - (float)h);
            v = K*va1[e]; h = (_Float16)v; Ahi1[e]   = h; Alo1[e]   = (_Float16)(v - (float)h);
            v = K*vb1[e]; h = (_Float16)v; Ahi1[e+4] = h; Alo1[e+4] = (_Float16)(v - (float)h);
        }
    }

    // ---- C-init constants: D reg r -> h-index 32wc + 8g + 4wh + r ----
    float wihc[4], biasc[4];
#pragma unroll
    for (int r = 0; r < 4; ++r) {
        const int idx = 32*wc + 8*g + 4*wh + r;
        wihc[r]  = K * W_ih[idx];
        biasc[r] = K * (b_ih[idx] + b_hh[idx]);
    }

    // zero exchange buffer: h(0) = 0 (published by first staging barrier)
    {
        const u32x4 z = {0u, 0u, 0u, 0u};
        ((u32x4*)st)[tid] = z;                  // 256 x 16B = all 4 KB
    }

    const int sm = tid >> 4;                    // x staging: batch row
    const int tq = tid & 15;                    // t-quad
    const f32x4 zero4 = {0.f, 0.f, 0.f, 0.f};

    float hv0 = 0.f, hv1 = 0.f, hv2 = 0.f, hv3 = 0.f;

#pragma unroll 1
    for (int tc = 0; tc < TDIM/64; ++tc) {
        const f32x4 xv4 = *(const f32x4*)(x + (size_t)(gb0 + sm) * TDIM
                                            + tc*64 + tq*4);
        xs[tq*4 + 0][sm] = xv4.x;
        xs[tq*4 + 1][sm] = xv4.y;
        xs[tq*4 + 2][sm] = xv4.z;
        xs[tq*4 + 3][sm] = xv4.w;
        __syncthreads();    // publish xs (and the zeroed st at tc==0)

#pragma unroll 1
        for (int tj = 0; tj < 64; ++tj) {
            // h(t): published by the previous step's trailing barrier
            const f16x8 ih0 = __builtin_bit_cast(f16x8, *(const u32x4*)&st[0][lane][0]);
            const f16x8 ih1 = __builtin_bit_cast(f16x8, *(const u32x4*)&st[1][lane][0]);
            const f16x8 il0 = __builtin_bit_cast(f16x8, *(const u32x4*)&st[2][lane][0]);
            const f16x8 il1 = __builtin_bit_cast(f16x8, *(const u32x4*)&st[3][lane][0]);
            const float xt = xs[tj][b];

            f32x4 c1, c2, c3;
            c1.x = fmaf(xt, wihc[0], biasc[0]);
            c1.y = fmaf(xt, wihc[1], biasc[1]);
            c1.z = fmaf(xt, wihc[2], biasc[2]);
            c1.w = fmaf(xt, wihc[3], biasc[3]);
            c2 = zero4; c3 = zero4;

            // three 2-deep chains: (Whi+Wlo)(hhi+hlo) ~ hi*hi + hi*lo + lo*hi
            c1 = __builtin_amdgcn_mfma_f32_16x16x32_f16(Ahi0, ih0, c1, 0, 0, 0);
            c2 = __builtin_amdgcn_mfma_f32_16x16x32_f16(Ahi0, il0, c2, 0, 0, 0);
            c3 = __builtin_amdgcn_mfma_f32_16x16x32_f16(Alo0, ih0, c3, 0, 0, 0);
            c1 = __builtin_amdgcn_mfma_f32_16x16x32_f16(Ahi1, ih1, c1, 0, 0, 0);
            c2 = __builtin_amdgcn_mfma_f32_16x16x32_f16(Ahi1, il1, c2, 0, 0, 0);
            c3 = __builtin_amdgcn_mfma_f32_16x16x32_f16(Alo1, ih1, c3, 0, 0, 0);

            // tanh(z) = 1 - 2/(1 + e^{2z}); inputs already K-scaled
            const float z0 = c1.x + (c2.x + c3.x);
            const float z1 = c1.y + (c2.y + c3.y);
            const float z2 = c1.z + (c2.z + c3.z);
            const float z3 = c1.w + (c2.w + c3.w);
            hv0 = fmaf(-2.0f, __builtin_amdgcn_rcpf(__builtin_amdgcn_exp2f(z0) + 1.0f), 1.0f);
            hv1 = fmaf(-2.0f, __builtin_amdgcn_rcpf(__builtin_amdgcn_exp2f(z1) + 1.0f), 1.0f);
            hv2 = fmaf(-2.0f, __builtin_amdgcn_rcpf(__builtin_amdgcn_exp2f(z2) + 1.0f), 1.0f);
            hv3 = fmaf(-2.0f, __builtin_amdgcn_rcpf(__builtin_amdgcn_exp2f(z3) + 1.0f), 1.0f);

            const float h0 = hi_mask(hv0), h1 = hi_mask(hv1);
            const float h2 = hi_mask(hv2), h3 = hi_mask(hv3);
            u32x2 nh, nl;
            nh.x = pk2(h0, h1);           nh.y = pk2(h2, h3);
            nl.x = pk2(hv0-h0, hv1-h1);   nl.y = pk2(hv2-h2, hv3-h3);

            __syncthreads();   // barrier 1: every wave is done reading h(t)
            *(u32x2*)&st[wc][lane][2*wh]   = nh;   // h(t+1) hi, dwords 2w,2w+1
            *(u32x2*)&st[2+wc][lane][2*wh] = nl;   // h(t+1) lo
            __syncthreads();   // barrier 2: h(t+1) visible to all waves
        }
    }

    // ---- out[b] = sum_j h[j]*fc_w[j] + fc_b ----
    // Lane's own 4 final h-values (exact f32 from the last step):
    // indices 32wc + 8g + 4wh + r, disjoint cover over (w, g, r).
    float acc = 0.0f;
    acc = fmaf(hv0, fc_w[32*wc + 8*g + 4*wh + 0], acc);
    acc = fmaf(hv1, fc_w[32*wc + 8*g + 4*wh + 1], acc);
    acc = fmaf(hv2, fc_w[32*wc + 8*g + 4*wh + 2], acc);
    acc = fmaf(hv3, fc_w[32*wc + 8*g + 4*wh + 3], acc);
    acc += __shfl_xor(acc, 16, 64);   // sum the 4 g-groups of this batch col
    acc += __shfl_xor(acc, 32, 64);
    if (lane < 16) red[w][lane] = acc;
    __syncthreads();
    if (tid < GB)
        out[gb0 + tid] = red[0][tid] + red[1][tid] + red[2][tid] + red[3][tid]
                       + fc_b[0];
}

extern "C" void kernel_launch(void* const* d_in, const int* in_sizes, int n_in,
                              void* d_out, int out_size, void* d_ws, size_t ws_size,
                              hipStream_t stream)
{
    const float* x    = (const float*)d_in[0];
    const float* W_ih = (const float*)d_in[1];
    const float* W_hh = (const float*)d_in[2];
    const float* b_ih = (const float*)d_in[3];
    const float* b_hh = (const float*)d_in[4];
    const float* fc_w = (const float*)d_in[5];
    const float* fc_b = (const float*)d_in[6];
    float* out = (float*)d_out;

    const int B = in_sizes[0] / TDIM;      // x is (B, T, 1)
    const int blocks = B / GB;             // 256 blocks x 4 waves = full chip

    rnn_quadwave<<<blocks, 256, 0, stream>>>(
        x, W_ih, W_hh, b_ih, b_hh, fc_w, fc_b, out, B);
}

// Round 10
// 226.499 us; speedup vs baseline: 1.4957x; 1.1445x over previous
//
#include <hip/hip_runtime.h>
#include <stdint.h>

#define HDIM 64
#define TDIM 512
#define GB   16   // batches per block (one MFMA N-tile)

// ---- 4-wave MFMA RNN, ping-pong state, ONE barrier per step ----
// r9 (verified, 964 cy/step): read -> compute -> BARRIER -> write -> BARRIER.
// Counters: VALU 278 cy, MFMA 96 cy, conflicts 40 cy => ~550 cy/step stall,
// dominated by 2x (waitcnt-drain + barrier handshake) on a 1-wave/SIMD grid.
// r10: ping-pong state buffer (r4-verified protocol) removes barrier 1:
//   step t reads st[t&1], writes st[(t&1)^1], single barrier at end.
//   Safety: reads of a buffer complete before step t's barrier; the
//   conflicting write happens in step t+1, after it.
// Also: 6 independent depth-1 MFMA accumulators (was 3 chains of 2) --
// shaves one MFMA-latency off the serial chain for +12 VALU adds.
// All mappings/numerics byte-identical to r9 (absmax 0.001953):
//   transposed update S_new[64h x 16b] = tanh(xw + W'*S), state=B-operand,
//   phi(16w+4g+r) = 32*(w>>1)+8g+4*(w&1)+r on W_hh rows/W_ih/bias/fc_w,
//   f16 hi/lo 3-term product, K=2*log2(e) folded in, bit-mask hi split,
//   cvt_pkrtz pack. Wave w writes dwords [2*(w&1)] of chunk w>>1.
// 256 blocks x 4 waves = 1024 waves = 1/SIMD, full chip.

typedef float    f32x4 __attribute__((ext_vector_type(4)));
typedef _Float16 f16x8 __attribute__((ext_vector_type(8)));
typedef _Float16 f16x2 __attribute__((ext_vector_type(2)));
typedef unsigned int u32;
typedef unsigned int u32x2 __attribute__((ext_vector_type(2)));
typedef unsigned int u32x4 __attribute__((ext_vector_type(4)));

__device__ __forceinline__ u32 pk2(float a, float b) {
    return __builtin_bit_cast(u32, __builtin_amdgcn_cvt_pkrtz(a, b));
}
__device__ __forceinline__ float hi_mask(float v) {
    // top-13-mantissa-bit truncation: exactly f16-representable for |v|<=1
    return __builtin_bit_cast(float, __builtin_bit_cast(u32, v) & 0xFFFFE000u);
}

__global__ __launch_bounds__(256, 1)
__attribute__((amdgpu_waves_per_eu(1)))
void rnn_pingpong(const float* __restrict__ x,
                  const float* __restrict__ W_ih,
                  const float* __restrict__ W_hh,
                  const float* __restrict__ b_ih,
                  const float* __restrict__ b_hh,
                  const float* __restrict__ fc_w,
                  const float* __restrict__ fc_b,
                  float* __restrict__ out,
                  int B)
{
    // [pingpong][quad][lane][dword]; quads: 0=hi-c0 1=hi-c1 2=lo-c0 3=lo-c1
    __shared__ __align__(16) u32 st[2][4][64][4];   // 8 KB
    __shared__ float xs[64][GB];                    // 4 KB x chunk [t][batch]
    __shared__ float red[4][GB];                    // final reduction

    const int tid  = threadIdx.x;               // block = 4 waves
    const int lane = tid & 63;
    const int w    = tid >> 6;                  // wave id = output tile
    const int b    = lane & 15;                 // batch col (B/D col)
    const int g    = lane >> 4;                 // k-group / D row-group
    const int m16  = lane & 15;
    const int gb0  = blockIdx.x * GB;
    const int wc   = w >> 1;                    // chunk this wave feeds
    const int wh   = w & 1;                     // dword-pair within chunk

    const float K = 2.885390081777927f;         // 2*log2(e), folded into W & bias

    // ---- A-frags (tile w): rows phi(16w + m16), f16 hi/lo, K-scaled ----
    f16x8 Ahi0, Ahi1, Alo0, Alo1;               // chunk 0 / chunk 1
    {
        const int wr = 32*wc + 8*(m16 >> 2) + 4*wh + (m16 & 3);
        const float* wrow = W_hh + wr * HDIM;
        const f32x4 va0 = *(const f32x4*)(wrow + 8*g);
        const f32x4 vb0 = *(const f32x4*)(wrow + 8*g + 4);
        const f32x4 va1 = *(const f32x4*)(wrow + 32 + 8*g);
        const f32x4 vb1 = *(const f32x4*)(wrow + 32 + 8*g + 4);
#pragma unroll
        for (int e = 0; e < 4; ++e) {
            float v; _Float16 h;
            v = K*va0[e]; h = (_Float16)v; Ahi0[e]   = h; Alo0[e]   = (_Float16)(v - (float)h);
            v = K*vb0[e]; h = (_Float16)v; Ahi0[e+4] = h; Alo0[e+4] = (_Float16)(v - (float)h);
            v = K*va1[e]; h = (_Float16)v; Ahi1[e]   = h; Alo1[e]   = (_Float16)(v - (float)h);
            v = K*vb1[e]; h = (_Float16)v; Ahi1[e+4] = h; Alo1[e+4] = (_Float16)(v - (float)h);
        }
    }

    // ---- C-init constants: D reg r -> h-index 32wc + 8g + 4wh + r ----
    float wihc[4], biasc[4];
#pragma unroll
    for (int r = 0; r < 4; ++r) {
        const int idx = 32*wc + 8*g + 4*wh + r;
        wihc[r]  = K * W_ih[idx];
        biasc[r] = K * (b_ih[idx] + b_hh[idx]);
    }

    // zero BOTH ping-pong state buffers: h(0)=0 (only buf 0 is read at t=0,
    // but zeroing all 8 KB is one-off and simple). Published by barrier 1.
    {
        const u32x4 z = {0u, 0u, 0u, 0u};
        ((u32x4*)st)[tid]       = z;            // 256 x 16B = 4 KB
        ((u32x4*)st)[tid + 256] = z;            // + 4 KB
    }

    const int sm = tid >> 4;                    // x staging: batch row
    const int tq = tid & 15;                    // t-quad
    const f32x4 zero4 = {0.f, 0.f, 0.f, 0.f};

    float hv0 = 0.f, hv1 = 0.f, hv2 = 0.f, hv3 = 0.f;

#pragma unroll 1
    for (int tc = 0; tc < TDIM/64; ++tc) {
        const f32x4 xv4 = *(const f32x4*)(x + (size_t)(gb0 + sm) * TDIM
                                            + tc*64 + tq*4);
        xs[tq*4 + 0][sm] = xv4.x;
        xs[tq*4 + 1][sm] = xv4.y;
        xs[tq*4 + 2][sm] = xv4.z;
        xs[tq*4 + 3][sm] = xv4.w;
        __syncthreads();    // publish xs (and the zeroed st at tc==0)

#pragma unroll 1
        for (int tj = 0; tj < 64; ++tj) {
            const int pp = tj & 1;      // global parity: tc*64 is even
            // h(t) from read buffer (published by previous step's barrier)
            const f16x8 ih0 = __builtin_bit_cast(f16x8, *(const u32x4*)&st[pp][0][lane][0]);
            const f16x8 ih1 = __builtin_bit_cast(f16x8, *(const u32x4*)&st[pp][1][lane][0]);
            const f16x8 il0 = __builtin_bit_cast(f16x8, *(const u32x4*)&st[pp][2][lane][0]);
            const f16x8 il1 = __builtin_bit_cast(f16x8, *(const u32x4*)&st[pp][3][lane][0]);
            const float xt = xs[tj][b];

            f32x4 c1, c1b, c2, c2b, c3, c3b;
            c1.x = fmaf(xt, wihc[0], biasc[0]);
            c1.y = fmaf(xt, wihc[1], biasc[1]);
            c1.z = fmaf(xt, wihc[2], biasc[2]);
            c1.w = fmaf(xt, wihc[3], biasc[3]);
            c1b = zero4; c2 = zero4; c2b = zero4; c3 = zero4; c3b = zero4;

            // six independent depth-1 MFMAs (hi*hi + hi*lo + lo*hi, 2 chunks)
            c1  = __builtin_amdgcn_mfma_f32_16x16x32_f16(Ahi0, ih0, c1,  0, 0, 0);
            c1b = __builtin_amdgcn_mfma_f32_16x16x32_f16(Ahi1, ih1, c1b, 0, 0, 0);
            c2  = __builtin_amdgcn_mfma_f32_16x16x32_f16(Ahi0, il0, c2,  0, 0, 0);
            c2b = __builtin_amdgcn_mfma_f32_16x16x32_f16(Ahi1, il1, c2b, 0, 0, 0);
            c3  = __builtin_amdgcn_mfma_f32_16x16x32_f16(Alo0, ih0, c3,  0, 0, 0);
            c3b = __builtin_amdgcn_mfma_f32_16x16x32_f16(Alo1, ih1, c3b, 0, 0, 0);

            const f32x4 zsum = (c1 + c1b) + ((c2 + c2b) + (c3 + c3b));

            // tanh(z) = 1 - 2/(1 + e^{2z}); inputs already K-scaled
            hv0 = fmaf(-2.0f, __builtin_amdgcn_rcpf(__builtin_amdgcn_exp2f(zsum.x) + 1.0f), 1.0f);
            hv1 = fmaf(-2.0f, __builtin_amdgcn_rcpf(__builtin_amdgcn_exp2f(zsum.y) + 1.0f), 1.0f);
            hv2 = fmaf(-2.0f, __builtin_amdgcn_rcpf(__builtin_amdgcn_exp2f(zsum.z) + 1.0f), 1.0f);
            hv3 = fmaf(-2.0f, __builtin_amdgcn_rcpf(__builtin_amdgcn_exp2f(zsum.w) + 1.0f), 1.0f);

            const float h0 = hi_mask(hv0), h1 = hi_mask(hv1);
            const float h2 = hi_mask(hv2), h3 = hi_mask(hv3);
            u32x2 nh, nl;
            nh.x = pk2(h0, h1);           nh.y = pk2(h2, h3);
            nl.x = pk2(hv0-h0, hv1-h1);   nl.y = pk2(hv2-h2, hv3-h3);

            // write h(t+1) into the OTHER buffer; one barrier publishes it.
            // (Write-after-read safe: reads of st[pp^1] happened in step
            //  t-1, before its barrier.)
            *(u32x2*)&st[pp ^ 1][wc][lane][2*wh]     = nh;
            *(u32x2*)&st[pp ^ 1][2 + wc][lane][2*wh] = nl;
            __syncthreads();
        }
    }

    // ---- out[b] = sum_j h[j]*fc_w[j] + fc_b ----
    // Lane's 4 final h-values (exact f32): indices 32wc + 8g + 4wh + r.
    float acc = 0.0f;
    acc = fmaf(hv0, fc_w[32*wc + 8*g + 4*wh + 0], acc);
    acc = fmaf(hv1, fc_w[32*wc + 8*g + 4*wh + 1], acc);
    acc = fmaf(hv2, fc_w[32*wc + 8*g + 4*wh + 2], acc);
    acc = fmaf(hv3, fc_w[32*wc + 8*g + 4*wh + 3], acc);
    acc += __shfl_xor(acc, 16, 64);   // sum the 4 g-groups of this batch col
    acc += __shfl_xor(acc, 32, 64);
    if (lane < 16) red[w][lane] = acc;
    __syncthreads();
    if (tid < GB)
        out[gb0 + tid] = red[0][tid] + red[1][tid] + red[2][tid] + red[3][tid]
                       + fc_b[0];
}

extern "C" void kernel_launch(void* const* d_in, const int* in_sizes, int n_in,
                              void* d_out, int out_size, void* d_ws, size_t ws_size,
                              hipStream_t stream)
{
    const float* x    = (const float*)d_in[0];
    const float* W_ih = (const float*)d_in[1];
    const float* W_hh = (const float*)d_in[2];
    const float* b_ih = (const float*)d_in[3];
    const float* b_hh = (const float*)d_in[4];
    const float* fc_w = (const float*)d_in[5];
    const float* fc_b = (const float*)d_in[6];
    float* out = (float*)d_out;

    const int B = in_sizes[0] / TDIM;      // x is (B, T, 1)
    const int blocks = B / GB;             // 256 blocks x 4 waves = full chip

    rnn_pingpong<<<blocks, 256, 0, stream>>>(
        x, W_ih, W_hh, b_ih, b_hh, fc_w, fc_b, out, B);
}